// Round 1
// 178.807 us; speedup vs baseline: 1.0475x; 1.0475x over previous
//
#include <hip/hip_runtime.h>
#include <math.h>

#define DD 64
#define CC 128
#define HH 512
#define BATCH 4096

typedef __attribute__((ext_vector_type(2))) float f32x2;

__device__ __forceinline__ f32x2 splat2(float x) { f32x2 v; v[0] = x; v[1] = x; return v; }

// Deterministic packed FMA: d = a*b + c on both halves. LLVM rarely forms
// v_pk_fma_f32 from generic vector IR; force it. 64-bit "v" operands print
// as aligned VGPR pairs.
__device__ __forceinline__ f32x2 pk_fma(f32x2 a, f32x2 b, f32x2 c) {
    f32x2 d;
    asm("v_pk_fma_f32 %0, %1, %2, %3" : "=v"(d) : "v"(a), "v"(b), "v"(c));
    return d;
}

__device__ __forceinline__ float fast_softplus(float x) {
    float t = exp2f(-fabsf(x) * 1.44269504f);
    return fmaxf(x, 0.f) + 0.69314718f * log2f(1.f + t);
}

// wave-uniform broadcast via v_readlane (no DS unit); result is SGPR-resident,
// scalar consumers can use it as the 1 allowed SGPR source of v_fmac_f32.
__device__ __forceinline__ float bcast(float x, int l) {
    return __int_as_float(__builtin_amdgcn_readlane(__float_as_int(x), l));
}

typedef const __attribute__((address_space(1))) void* as1_cptr;
typedef __attribute__((address_space(3))) void* as3_ptr;
__device__ __forceinline__ void glds16(const float* g, float* l) {
    // 16B from per-lane address g -> ldsbase + lane*16 (dest wave-uniform)
    __builtin_amdgcn_global_load_lds((as1_cptr)g, (as3_ptr)l, 16, 0, 0);
}

// One block = 4 waves x R=2 rows = 8 batch rows; grid 512 -> 2 blocks/CU.
// Lane l owns hidden units 8l..8l+7 (deg = (j%63)+1), split-half LDS layout
// (elements 8l..8l+3 at +16B*l, 8l+4..8l+7 at +1KB+16B*l) -> conflict-free b128.
//
// vs previous round: (1) all p1/p2 accumulations via forced v_pk_fma_f32;
// (2) W3 rows staged to LDS (pairs of 512B rows per glds16, per-lane source
//     row select, linear dest) -> phase (d) is 2 ds_read_b32/t, no flat loads,
//     no 64-bit addr math, 4x less L2 traffic;
// (3) dead work removed: t=8 rank row exists only for base<8 (i<=8);
//     phases (a)-(d) skipped at i==0 (h == 0 contributes nothing);
// (4) deg[u]==i compares shared between (a) and (c).
__global__ __launch_bounds__(256, 2) void made_sample(
    const float* __restrict__ ctx,   // (B, C)
    const float* __restrict__ eps,   // (B, D)
    const float* __restrict__ W1,    // (D+C, H)
    const float* __restrict__ b1,    // (H)
    const float* __restrict__ W2,    // (H, H)
    const float* __restrict__ b2,    // (H)
    const float* __restrict__ W3,    // (H, 2D)
    const float* __restrict__ b3,    // (2D)
    float* __restrict__ out)         // (B, D)
{
    const int lane  = threadIdx.x & 63;
    const int w     = threadIdx.x >> 6;          // wave 0..3
    const int rbase = blockIdx.x * 8 + w * 2;    // 2 batch rows per wave
    const int jbase = 8 * lane;

    __shared__ float sbuf[2][10 * HH];           // 2 x 20 KB (slots: 9 W2 + 1 W1)
    __shared__ float w3sb[2][5 * 256];           // 2 x 5 KB  (5 pairs of W3 rows)

    int deg[8];
    #pragma unroll
    for (int u = 0; u < 8; ++u) deg[u] = (jbase + u) % 63 + 1;

    // split-half LDS read: slot base -> 4 f32x2 (8 floats) for this lane
    auto load8v = [&](const float* base_, f32x2* r_) {
        float4 a = *(const float4*)(base_ + lane * 4);
        float4 b = *(const float4*)(base_ + 256 + lane * 4);
        r_[0][0] = a.x; r_[0][1] = a.y; r_[1][0] = a.z; r_[1][1] = a.w;
        r_[2][0] = b.x; r_[2][1] = b.y; r_[3][0] = b.z; r_[3][1] = b.w;
    };
    // stage one 512-float row into split-half layout (2 glds16)
    auto stage_row = [&](const float* src, float* dst) {
        glds16(src + lane * 8,     dst);
        glds16(src + lane * 8 + 4, dst + 256);
    };
    // stage W3 rows k0,k1 (128 floats each) into one 1KB pair slot:
    // lanes 0..31 carry row k0 (bytes 0..511), lanes 32..63 row k1 (512..1023).
    auto stage_w3pair = [&](int k0, int k1, float* dst) {
        const float* g = (lane < 32) ? (W3 + k0 * (2 * DD) + lane * 4)
                                     : (W3 + k1 * (2 * DD) + (lane - 32) * 4);
        glds16(g, dst);
    };

    f32x2 p1[2][4], p2[2][4], acc[2];
    #pragma unroll
    for (int j = 0; j < 4; ++j) {
        f32x2 t1, t2;
        t1[0] = b1[jbase + 2 * j]; t1[1] = b1[jbase + 2 * j + 1];
        t2[0] = b2[jbase + 2 * j]; t2[1] = b2[jbase + 2 * j + 1];
        p1[0][j] = t1; p1[1][j] = t1;
        p2[0][j] = t2; p2[1][j] = t2;
    }
    acc[0] = splat2(0.f);
    acc[1] = splat2(0.f);

    float ca[2], cb[2], ep[2];
    #pragma unroll
    for (int r = 0; r < 2; ++r) {
        ca[r] = ctx[(rbase + r) * CC + lane];
        cb[r] = ctx[(rbase + r) * CC + 64 + lane];
        ep[r] = eps[(rbase + r) * DD + lane];
    }
    const float b3m = b3[lane];        // bias for mean col `lane`
    const float b3p = b3[64 + lane];   // bias for prescale col `lane`

    // ctx chunk ch: W1 rows DD+8ch..DD+8ch+7 -> slots 0..7 (2 rows per wave)
    auto stage_ctx = [&](int ch, float* buf) {
        #pragma unroll
        for (int q2 = 0; q2 < 2; ++q2) {
            const int q = 2 * w + q2;
            stage_row(W1 + (DD + 8 * ch + q) * HH, buf + q * HH);
        }
    };
    // staging for main step `in`:
    //   W2 rows basen+63t -> slots 0..7 (waves: slot w and 4+w)
    //   slot 8 (t=8, row basen+504) only when basen<8        (wave 0)
    //   W1 row `in` -> slot 9                                 (wave 1)
    //   W3 pairs p=0..3 -> w3buf (waves 2,3), pair 4 cond     (wave 0)
    auto stage_step = [&](int in, float* buf, float* w3buf) {
        if (in == 0) {                       // step 0 needs only W1 row 0
            if (w == 1) stage_row(W1, buf + 9 * HH);
            return;
        }
        const int basen = in - 1;
        const bool h9n = basen < 8;
        stage_row(W2 + (basen + 63 * w) * HH,       buf + w * HH);
        stage_row(W2 + (basen + 63 * (4 + w)) * HH, buf + (4 + w) * HH);
        if (w == 1) stage_row(W1 + in * HH, buf + 9 * HH);
        if (w == 0 && h9n) {
            stage_row(W2 + (basen + 504) * HH, buf + 8 * HH);
            stage_w3pair(basen + 504, basen + 504, w3buf + 4 * 256);
        }
        if (w >= 2) {
            #pragma unroll
            for (int pp = 0; pp < 2; ++pp) {
                const int p = 2 * (w - 2) + pp;     // waves 2,3 -> pairs 0..3
                stage_w3pair(basen + 63 * (2 * p), basen + 63 * (2 * p + 1),
                             w3buf + p * 256);
            }
        }
    };

    // ---- context init: pre1 += ctx @ W1[D:,:], 16 chunks of 8 rows ----
    stage_ctx(0, sbuf[0]);
    __syncthreads();
    #pragma unroll 1
    for (int ch = 0; ch < 16; ++ch) {
        float* cur = sbuf[ch & 1];
        float* nxt = sbuf[(ch + 1) & 1];
        if (ch < 15) stage_ctx(ch + 1, nxt);
        else         stage_step(0, sbuf[0], w3sb[0]);   // (16)&1==0: parity OK
        #pragma unroll
        for (int q = 0; q < 8; ++q) {
            f32x2 wv[4];
            load8v(cur + q * HH, wv);
            const int c = 8 * ch + q;
            #pragma unroll
            for (int r = 0; r < 2; ++r) {
                const float cv = bcast((ch < 8) ? ca[r] : cb[r], c & 63);
                const f32x2 cv2 = splat2(cv);
                #pragma unroll
                for (int j = 0; j < 4; ++j) p1[r][j] = pk_fma(cv2, wv[j], p1[r][j]);
            }
        }
        __syncthreads();
    }

    float z[2] = {0.f, 0.f};

    // ---- autoregressive main loop ----
    #pragma unroll 1
    for (int i = 0; i < DD; ++i) {
        float* cur = sbuf[i & 1];
        const float* w3s = w3sb[i & 1];
        if (i < 63) stage_step(i + 1, sbuf[(i + 1) & 1], w3sb[(i + 1) & 1]);

        if (i > 0) {                      // i==0: no unit has deg==0, all h==0
            const int base = i - 1;
            const bool h9 = base < 8;     // 9th finalizing unit exists (i<=8)

            // (a) select finalized h1 (deg==i); compares shared with (c)
            float m0 = 0.f, m1 = 0.f;
            #pragma unroll
            for (int u = 0; u < 8; ++u) {
                const bool e = (deg[u] == i);
                m0 = e ? p1[0][u >> 1][u & 1] : m0;
                m1 = e ? p1[1][u >> 1][u & 1] : m1;
            }
            m0 = fmaxf(m0, 0.f);
            m1 = fmaxf(m1, 0.f);

            // (b) rank update of pre2 from LDS W2 rows (packed FMA)
            #pragma unroll
            for (int t = 0; t < 8; ++t) {
                const int k = base + 63 * t;
                f32x2 wv[4];
                load8v(cur + t * HH, wv);
                const f32x2 h0 = splat2(bcast(m0, k >> 3));
                const f32x2 h1 = splat2(bcast(m1, k >> 3));
                #pragma unroll
                for (int j = 0; j < 4; ++j) {
                    p2[0][j] = pk_fma(h0, wv[j], p2[0][j]);
                    p2[1][j] = pk_fma(h1, wv[j], p2[1][j]);
                }
            }
            if (h9) {                     // t=8: unit base+504, owner lane 63
                f32x2 wv[4];
                load8v(cur + 8 * HH, wv);
                const f32x2 h0 = splat2(bcast(m0, 63));
                const f32x2 h1 = splat2(bcast(m1, 63));
                #pragma unroll
                for (int j = 0; j < 4; ++j) {
                    p2[0][j] = pk_fma(h0, wv[j], p2[0][j]);
                    p2[1][j] = pk_fma(h1, wv[j], p2[1][j]);
                }
            }

            // (c) capture newly-final h2 (deg==i)
            float g0 = 0.f, g1 = 0.f;
            #pragma unroll
            for (int u = 0; u < 8; ++u) {
                const bool e = (deg[u] == i);
                g0 = e ? p2[0][u >> 1][u & 1] : g0;
                g1 = e ? p2[1][u >> 1][u & 1] : g1;
            }
            g0 = fmaxf(g0, 0.f);
            g1 = fmaxf(g1, 0.f);

            // (d) incremental W3 accumulation from LDS-staged rows.
            // scalar v_fmac with SGPR h-operand beats pk+splat here (1-reg acc).
            #pragma unroll
            for (int t = 0; t < 8; ++t) {
                const int k = base + 63 * t;
                const float wa = w3s[t * 128 + lane];        // W3[k, lane]
                const float wb = w3s[t * 128 + 64 + lane];   // W3[k, 64+lane]
                const float h0 = bcast(g0, k >> 3);
                const float h1 = bcast(g1, k >> 3);
                acc[0][0] = fmaf(h0, wa, acc[0][0]);
                acc[0][1] = fmaf(h0, wb, acc[0][1]);
                acc[1][0] = fmaf(h1, wa, acc[1][0]);
                acc[1][1] = fmaf(h1, wb, acc[1][1]);
            }
            if (h9) {
                const float wa = w3s[8 * 128 + lane];
                const float wb = w3s[8 * 128 + 64 + lane];
                const float h0 = bcast(g0, 63);
                const float h1 = bcast(g1, 63);
                acc[0][0] = fmaf(h0, wa, acc[0][0]);
                acc[0][1] = fmaf(h0, wb, acc[0][1]);
                acc[1][0] = fmaf(h1, wa, acc[1][0]);
                acc[1][1] = fmaf(h1, wb, acc[1][1]);
            }
        }

        // (e) z_i: column i's totals live in lane i; every lane computes its own
        // candidate (parallel), one readlane extracts the real one; feed back.
        {
            f32x2 w1v[4];
            load8v(cur + 9 * HH, w1v);
            #pragma unroll
            for (int r = 0; r < 2; ++r) {
                const float am = acc[r][0] + b3m;
                const float ap = acc[r][1] + b3p;
                const float sp = fast_softplus(ap);
                const float zc = fmaf(sp, ep[r], am);
                const float zi = bcast(zc, i);
                if (lane == i) z[r] = zi;
                const f32x2 zi2 = splat2(zi);
                #pragma unroll
                for (int j = 0; j < 4; ++j) p1[r][j] = pk_fma(zi2, w1v[j], p1[r][j]);
            }
        }

        __syncthreads();
    }

    #pragma unroll
    for (int r = 0; r < 2; ++r) out[(rbase + r) * DD + lane] = z[r];
}

extern "C" void kernel_launch(void* const* d_in, const int* in_sizes, int n_in,
                              void* d_out, int out_size, void* d_ws, size_t ws_size,
                              hipStream_t stream) {
    const float* ctx = (const float*)d_in[0];
    const float* eps = (const float*)d_in[1];
    const float* W1  = (const float*)d_in[2];
    const float* b1  = (const float*)d_in[3];
    const float* W2  = (const float*)d_in[4];
    const float* b2  = (const float*)d_in[5];
    const float* W3  = (const float*)d_in[6];
    const float* b3  = (const float*)d_in[7];
    (void)d_ws; (void)ws_size; (void)in_sizes; (void)n_in; (void)out_size;

    made_sample<<<BATCH / 8, 256, 0, stream>>>(ctx, eps, W1, b1, W2, b2, W3, b3,
                                               (float*)d_out);
}